// Round 1
// baseline (529.940 us; speedup 1.0000x reference)
//
#include <hip/hip_runtime.h>
#include <cstdint>
#include <cstddef>

#define HID 128

// ---------------- CSR build ----------------

__global__ __launch_bounds__(256) void k_zero_int(int* __restrict__ p, int n) {
  int i = blockIdx.x * 256 + threadIdx.x;
  if (i < n) p[i] = 0;
}

__global__ __launch_bounds__(256) void k_count(const int* __restrict__ dst,
                                               int* __restrict__ cnt, int E) {
  int i = blockIdx.x * 256 + threadIdx.x;
  if (i < E) atomicAdd(&cnt[dst[i]], 1);
}

// per-block inclusive scan of counts; rowptr1 = rowptr + 1
__global__ __launch_bounds__(256) void k_scan_blocks(const int* __restrict__ cnt,
                                                     int* __restrict__ rowptr1,
                                                     int* __restrict__ blksum, int n) {
  __shared__ int s[256];
  int tid = threadIdx.x;
  int i = blockIdx.x * 256 + tid;
  int v = (i < n) ? cnt[i] : 0;
  s[tid] = v;
  __syncthreads();
  #pragma unroll
  for (int off = 1; off < 256; off <<= 1) {
    int add = (tid >= off) ? s[tid - off] : 0;
    __syncthreads();
    s[tid] += add;
    __syncthreads();
  }
  if (i < n) rowptr1[i] = s[tid];
  if (tid == 255) blksum[blockIdx.x] = s[255];
}

// single-block exclusive scan of block sums (nblk <= 256)
__global__ __launch_bounds__(256) void k_scan_top(int* __restrict__ blksum, int nblk) {
  __shared__ int s[256];
  int tid = threadIdx.x;
  int v = (tid < nblk) ? blksum[tid] : 0;
  s[tid] = v;
  __syncthreads();
  #pragma unroll
  for (int off = 1; off < 256; off <<= 1) {
    int add = (tid >= off) ? s[tid - off] : 0;
    __syncthreads();
    s[tid] += add;
    __syncthreads();
  }
  if (tid < nblk) blksum[tid] = s[tid] - v;  // exclusive
}

// add block offsets; cursor[i] <- row start (cursor held counts on entry)
__global__ __launch_bounds__(256) void k_scan_add(const int* __restrict__ blkoff,
                                                  int* __restrict__ rowptr,
                                                  int* __restrict__ cursor, int n) {
  int i = blockIdx.x * 256 + threadIdx.x;
  if (i < n) {
    int add = blkoff[i >> 8];
    int incl = rowptr[i + 1] + add;
    rowptr[i + 1] = incl;
    cursor[i] = incl - cursor[i];
    if (i == 0) rowptr[0] = 0;
  }
}

__global__ __launch_bounds__(256) void k_fill(const int* __restrict__ src,
                                              const int* __restrict__ dst,
                                              int* __restrict__ cursor,
                                              int* __restrict__ csr, int E) {
  int i = blockIdx.x * 256 + threadIdx.x;
  if (i < E) {
    int pos = atomicAdd(&cursor[dst[i]], 1);
    csr[pos] = src[i];
  }
}

// ---------------- mean aggregation: one wave per node ----------------

__global__ __launch_bounds__(256) void k_aggregate(const float* __restrict__ feat,
                                                   const int* __restrict__ rowptr,
                                                   const int* __restrict__ csr,
                                                   float* __restrict__ outmean, int N) {
  int wid = blockIdx.x * 4 + (threadIdx.x >> 6);
  int lane = threadIdx.x & 63;
  if (wid >= N) return;
  int start = rowptr[wid];
  int end   = rowptr[wid + 1];
  float ax = 0.f, ay = 0.f;
  for (int base = start; base < end; base += 64) {
    int m = end - base;
    if (m > 64) m = 64;
    int sidx = 0;
    if (base + lane < end) sidx = csr[base + lane];
    for (int j = 0; j < m; ++j) {
      int s = __shfl(sidx, j, 64);
      const float2* row = (const float2*)(feat + (size_t)s * HID);
      float2 v = row[lane];
      ax += v.x;
      ay += v.y;
    }
  }
  int deg = end - start;
  float inv = 1.0f / (float)(deg > 1 ? deg : 1);
  float2 mv;
  mv.x = ax * inv;
  mv.y = ay * inv;
  ((float2*)(outmean + (size_t)wid * HID))[lane] = mv;
}

// ---------------- fused GEMM: out = act(A1@WL^T + A2@WR^T + b) ----------------
// M x 128, K = 128 per operand (256 total). 64-row tile per block, 256 threads,
// thread tile 4 rows x 8 cols.

__global__ __launch_bounds__(256) void k_gemm_fused(const float* __restrict__ A1,
                                                    const float* __restrict__ A2,
                                                    const float* __restrict__ WL,
                                                    const float* __restrict__ WR,
                                                    const float* __restrict__ bias,
                                                    float* __restrict__ out,
                                                    int M, int do_relu) {
  __shared__ __align__(16) float sA[64][69];    // [row][k], +5 pad: 2-way bank alias only
  __shared__ __align__(16) float sW[64][132];   // [k][col], row stride 528B (16B-aligned)
  const int t  = threadIdx.x;
  const int tr = t & 15;   // row group: rows tr*4 .. tr*4+3
  const int tc = t >> 4;   // col group: cols tc*8 .. tc*8+7
  const int row0 = blockIdx.x * 64;

  float acc[4][8];
  #pragma unroll
  for (int j = 0; j < 4; ++j)
    #pragma unroll
    for (int i = 0; i < 8; ++i) acc[j][i] = 0.f;

  const int kq = (t & 15) * 4;  // staging: k quad
  const int rr = t >> 4;        // staging: row/col base

  for (int chunk = 0; chunk < 4; ++chunk) {
    const float* __restrict__ Asrc = (chunk < 2) ? A1 : A2;
    const float* __restrict__ Wsrc = (chunk < 2) ? WL : WR;
    const int k0 = (chunk & 1) * 64;
    // stage A tile (64 rows x 64 k), coalesced float4 reads
    #pragma unroll
    for (int p = 0; p < 4; ++p) {
      int r = rr + p * 16;
      int grow = row0 + r;
      float4 v = make_float4(0.f, 0.f, 0.f, 0.f);
      if (grow < M) v = *(const float4*)(Asrc + (size_t)grow * HID + k0 + kq);
      sA[r][kq + 0] = v.x; sA[r][kq + 1] = v.y; sA[r][kq + 2] = v.z; sA[r][kq + 3] = v.w;
    }
    // stage W tile transposed: sW[k][o] = W[o][k0+k]
    #pragma unroll
    for (int p = 0; p < 8; ++p) {
      int o = rr + p * 16;
      float4 v = *(const float4*)(Wsrc + (size_t)o * HID + k0 + kq);
      sW[kq + 0][o] = v.x; sW[kq + 1][o] = v.y; sW[kq + 2][o] = v.z; sW[kq + 3][o] = v.w;
    }
    __syncthreads();
    #pragma unroll 8
    for (int kk = 0; kk < 64; ++kk) {
      float4 w0 = *(const float4*)&sW[kk][tc * 8];
      float4 w1 = *(const float4*)&sW[kk][tc * 8 + 4];
      float a[4];
      #pragma unroll
      for (int j = 0; j < 4; ++j) a[j] = sA[tr * 4 + j][kk];
      #pragma unroll
      for (int j = 0; j < 4; ++j) {
        acc[j][0] += a[j] * w0.x; acc[j][1] += a[j] * w0.y;
        acc[j][2] += a[j] * w0.z; acc[j][3] += a[j] * w0.w;
        acc[j][4] += a[j] * w1.x; acc[j][5] += a[j] * w1.y;
        acc[j][6] += a[j] * w1.z; acc[j][7] += a[j] * w1.w;
      }
    }
    __syncthreads();
  }

  float4 bv0 = *(const float4*)(bias + tc * 8);
  float4 bv1 = *(const float4*)(bias + tc * 8 + 4);
  #pragma unroll
  for (int j = 0; j < 4; ++j) {
    int grow = row0 + tr * 4 + j;
    if (grow < M) {
      float4 o0, o1;
      o0.x = acc[j][0] + bv0.x; o0.y = acc[j][1] + bv0.y;
      o0.z = acc[j][2] + bv0.z; o0.w = acc[j][3] + bv0.w;
      o1.x = acc[j][4] + bv1.x; o1.y = acc[j][5] + bv1.y;
      o1.z = acc[j][6] + bv1.z; o1.w = acc[j][7] + bv1.w;
      if (do_relu) {
        o0.x = fmaxf(o0.x, 0.f); o0.y = fmaxf(o0.y, 0.f);
        o0.z = fmaxf(o0.z, 0.f); o0.w = fmaxf(o0.w, 0.f);
        o1.x = fmaxf(o1.x, 0.f); o1.y = fmaxf(o1.y, 0.f);
        o1.z = fmaxf(o1.z, 0.f); o1.w = fmaxf(o1.w, 0.f);
      }
      *(float4*)(out + (size_t)grow * HID + tc * 8) = o0;
      *(float4*)(out + (size_t)grow * HID + tc * 8 + 4) = o1;
    }
  }
}

// ---------------- fused mean-pool + classifier ----------------

__device__ __forceinline__ int lower_bound_dev(const int* a, int n, int key) {
  int lo = 0, hi = n;
  while (lo < hi) {
    int mid = (lo + hi) >> 1;
    if (a[mid] < key) lo = mid + 1; else hi = mid;
  }
  return lo;
}

__global__ __launch_bounds__(256) void k_pool_classify(const float* __restrict__ h,
                                                       const int* __restrict__ batch,
                                                       const float* __restrict__ cw,
                                                       const float* __restrict__ cb,
                                                       float* __restrict__ out, int N) {
  __shared__ int s_bounds[2];
  __shared__ float s_part[2][128];
  __shared__ float s_pool[128];
  int g = blockIdx.x;
  int t = threadIdx.x;
  if (t == 0) {
    s_bounds[0] = lower_bound_dev(batch, N, g);
    s_bounds[1] = lower_bound_dev(batch, N, g + 1);
  }
  __syncthreads();
  int lo = s_bounds[0], hi = s_bounds[1];
  int f = t & 127, half = t >> 7;
  float acc = 0.f;
  for (int n = lo + half; n < hi; n += 2) acc += h[(size_t)n * HID + f];
  s_part[half][f] = acc;
  __syncthreads();
  if (t < 128) {
    int cnt = hi - lo;
    float inv = 1.0f / (float)(cnt > 1 ? cnt : 1);
    s_pool[t] = (s_part[0][t] + s_part[1][t]) * inv;
  }
  __syncthreads();
  int o = t & 127, kh = t >> 7;
  float a2 = 0.f;
  #pragma unroll 4
  for (int k = kh * 64; k < kh * 64 + 64; ++k) a2 += s_pool[k] * cw[(size_t)o * HID + k];
  __syncthreads();
  s_part[kh][o] = a2;
  __syncthreads();
  if (t < 128) out[(size_t)g * HID + t] = s_part[0][t] + s_part[1][t] + cb[t];
}

// ---------------- launch ----------------

extern "C" void kernel_launch(void* const* d_in, const int* in_sizes, int n_in,
                              void* d_out, int out_size, void* d_ws, size_t ws_size,
                              hipStream_t stream) {
  const float* x     = (const float*)d_in[0];
  const int*   ei    = (const int*)d_in[1];
  const int*   batch = (const int*)d_in[2];
  const float* wl1   = (const float*)d_in[3];
  const float* b1    = (const float*)d_in[4];
  const float* wr1   = (const float*)d_in[5];
  const float* wl2   = (const float*)d_in[6];
  const float* b2    = (const float*)d_in[7];
  const float* wr2   = (const float*)d_in[8];
  const float* cw    = (const float*)d_in[9];
  const float* cb    = (const float*)d_in[10];
  float* out = (float*)d_out;

  const int N = in_sizes[0] / HID;   // 50000
  const int E = in_sizes[1] / 2;     // 800000
  const int G = out_size / HID;      // 128
  const int* src = ei;
  const int* dst = ei + E;

  char* w = (char*)d_ws;
  int* cursor = (int*)(w);                     // N ints (counts, then cursors)
  int* rowptr = (int*)(w + 262144);            // N+1 ints
  int* blks   = (int*)(w + 524288);            // <=256 ints
  int* csr    = (int*)(w + 528384);            // E ints
  size_t csr_bytes = ((size_t)E * 4 + 255) & ~(size_t)255;
  float* bufA = (float*)(w + 528384 + csr_bytes);   // N*128 floats (mean1 / mean2 / h2)
  float* bufB = bufA + (size_t)N * HID;             // N*128 floats (h1)

  const int nblkN = (N + 255) / 256;
  const int nblkE = (E + 255) / 256;
  const int aggBlocks  = (N + 3) / 4;
  const int gemmBlocks = (N + 63) / 64;

  hipLaunchKernelGGL(k_zero_int,    dim3(nblkN), dim3(256), 0, stream, cursor, N);
  hipLaunchKernelGGL(k_count,       dim3(nblkE), dim3(256), 0, stream, dst, cursor, E);
  hipLaunchKernelGGL(k_scan_blocks, dim3(nblkN), dim3(256), 0, stream, cursor, rowptr + 1, blks, N);
  hipLaunchKernelGGL(k_scan_top,    dim3(1),     dim3(256), 0, stream, blks, nblkN);
  hipLaunchKernelGGL(k_scan_add,    dim3(nblkN), dim3(256), 0, stream, blks, rowptr, cursor, N);
  hipLaunchKernelGGL(k_fill,        dim3(nblkE), dim3(256), 0, stream, src, dst, cursor, csr, E);

  // layer 1
  hipLaunchKernelGGL(k_aggregate,  dim3(aggBlocks),  dim3(256), 0, stream, x, rowptr, csr, bufA, N);
  hipLaunchKernelGGL(k_gemm_fused, dim3(gemmBlocks), dim3(256), 0, stream, bufA, x, wl1, wr1, b1, bufB, N, 1);
  // layer 2
  hipLaunchKernelGGL(k_aggregate,  dim3(aggBlocks),  dim3(256), 0, stream, bufB, rowptr, csr, bufA, N);
  hipLaunchKernelGGL(k_gemm_fused, dim3(gemmBlocks), dim3(256), 0, stream, bufA, bufB, wl2, wr2, b2, bufA, N, 1);
  // pool + classifier
  hipLaunchKernelGGL(k_pool_classify, dim3(G), dim3(256), 0, stream, bufA, batch, cw, cb, out, N);
}

// Round 2
// 392.711 us; speedup vs baseline: 1.3494x; 1.3494x over previous
//
#include <hip/hip_runtime.h>
#include <cstdint>
#include <cstddef>

#define HID 128
#define LDK 72   // LDS row stride in bf16 elems (64 + 8 pad; 144B stride, 16B-aligned, uniform bank spread)

typedef __attribute__((ext_vector_type(8))) short short8;
typedef __attribute__((ext_vector_type(4))) float floatx4;

__device__ __forceinline__ unsigned short f2bf(float f) {
  union { float f; uint32_t u; } c; c.f = f;
  uint32_t u = c.u;
  uint32_t r = (u + 0x7FFFu + ((u >> 16) & 1u)) >> 16;   // RNE
  return (unsigned short)r;
}
__device__ __forceinline__ float bflo(uint32_t v) { return __uint_as_float(v << 16); }
__device__ __forceinline__ float bfhi(uint32_t v) { return __uint_as_float(v & 0xFFFF0000u); }

// ---------------- CSR build ----------------

__global__ __launch_bounds__(256) void k_zero_int(int* __restrict__ p, int n) {
  int i = blockIdx.x * 256 + threadIdx.x;
  if (i < n) p[i] = 0;
}

__global__ __launch_bounds__(256) void k_count(const int* __restrict__ dst,
                                               int* __restrict__ cnt, int E) {
  int i = blockIdx.x * 256 + threadIdx.x;
  if (i < E) atomicAdd(&cnt[dst[i]], 1);
}

__global__ __launch_bounds__(256) void k_scan_blocks(const int* __restrict__ cnt,
                                                     int* __restrict__ rowptr1,
                                                     int* __restrict__ blksum, int n) {
  __shared__ int s[256];
  int tid = threadIdx.x;
  int i = blockIdx.x * 256 + tid;
  int v = (i < n) ? cnt[i] : 0;
  s[tid] = v;
  __syncthreads();
  #pragma unroll
  for (int off = 1; off < 256; off <<= 1) {
    int add = (tid >= off) ? s[tid - off] : 0;
    __syncthreads();
    s[tid] += add;
    __syncthreads();
  }
  if (i < n) rowptr1[i] = s[tid];
  if (tid == 255) blksum[blockIdx.x] = s[255];
}

__global__ __launch_bounds__(256) void k_scan_top(int* __restrict__ blksum, int nblk) {
  __shared__ int s[256];
  int tid = threadIdx.x;
  int v = (tid < nblk) ? blksum[tid] : 0;
  s[tid] = v;
  __syncthreads();
  #pragma unroll
  for (int off = 1; off < 256; off <<= 1) {
    int add = (tid >= off) ? s[tid - off] : 0;
    __syncthreads();
    s[tid] += add;
    __syncthreads();
  }
  if (tid < nblk) blksum[tid] = s[tid] - v;  // exclusive
}

__global__ __launch_bounds__(256) void k_scan_add(const int* __restrict__ blkoff,
                                                  int* __restrict__ rowptr,
                                                  int* __restrict__ cursor, int n) {
  int i = blockIdx.x * 256 + threadIdx.x;
  if (i < n) {
    int add = blkoff[i >> 8];
    int incl = rowptr[i + 1] + add;
    rowptr[i + 1] = incl;
    cursor[i] = incl - cursor[i];
    if (i == 0) rowptr[0] = 0;
  }
}

__global__ __launch_bounds__(256) void k_fill(const int* __restrict__ src,
                                              const int* __restrict__ dst,
                                              int* __restrict__ cursor,
                                              int* __restrict__ csr, int E) {
  int i = blockIdx.x * 256 + threadIdx.x;
  if (i < E) {
    int pos = atomicAdd(&cursor[dst[i]], 1);
    csr[pos] = src[i];
  }
}

// ---------------- fp32 -> bf16 cast (x), float4 -> 4x ushort ----------------

__global__ __launch_bounds__(256) void k_cast_bf16(const float* __restrict__ src,
                                                   unsigned short* __restrict__ dst, int n4) {
  int i = blockIdx.x * 256 + threadIdx.x;
  if (i < n4) {
    float4 v = ((const float4*)src)[i];
    uint32_t lo = (uint32_t)f2bf(v.x) | ((uint32_t)f2bf(v.y) << 16);
    uint32_t hi = (uint32_t)f2bf(v.z) | ((uint32_t)f2bf(v.w) << 16);
    ((uint2*)dst)[i] = make_uint2(lo, hi);
  }
}

// ---------------- mean aggregation, bf16 features: one wave per node ----------------

__global__ __launch_bounds__(256) void k_aggregate(const unsigned short* __restrict__ feat,
                                                   const int* __restrict__ rowptr,
                                                   const int* __restrict__ csr,
                                                   unsigned short* __restrict__ outmean, int N) {
  int wid = blockIdx.x * 4 + (threadIdx.x >> 6);
  int lane = threadIdx.x & 63;
  if (wid >= N) return;
  int start = rowptr[wid];
  int end   = rowptr[wid + 1];
  float ax = 0.f, ay = 0.f;
  for (int base = start; base < end; base += 64) {
    int m = end - base;
    if (m > 64) m = 64;
    int sidx = 0;
    if (base + lane < end) sidx = csr[base + lane];
    for (int j = 0; j < m; ++j) {
      int s = __shfl(sidx, j, 64);
      uint32_t v = ((const uint32_t*)(feat + (size_t)s * HID))[lane];
      ax += bflo(v);
      ay += bfhi(v);
    }
  }
  int deg = end - start;
  float inv = 1.0f / (float)(deg > 1 ? deg : 1);
  uint32_t packed = (uint32_t)f2bf(ax * inv) | ((uint32_t)f2bf(ay * inv) << 16);
  ((uint32_t*)(outmean + (size_t)wid * HID))[lane] = packed;
}

// ---------------- MFMA GEMM: out = relu(A1@WL^T + A2@WR^T + b), bf16 in/out ----------------
// 128x128 block tile, 4 waves, each wave 64x64 via 4x4 MFMA 16x16x32 tiles.
// K staged in 4 chunks of 64 (A1/WL k0..63, k64..127, then A2/WR).

__global__ __launch_bounds__(256, 2) void k_gemm_mfma(const unsigned short* __restrict__ A1,
                                                      const unsigned short* __restrict__ A2,
                                                      const float* __restrict__ WL,
                                                      const float* __restrict__ WR,
                                                      const float* __restrict__ bias,
                                                      unsigned short* __restrict__ outb,
                                                      int M, int relu) {
  __shared__ __align__(16) unsigned short sA[128 * LDK];
  __shared__ __align__(16) unsigned short sW[128 * LDK];
  const int t = threadIdx.x;
  const int lane = t & 63;
  const int wave = t >> 6;
  const int row0 = blockIdx.x * 128;
  const int mhalf = (wave & 1) * 64;
  const int nhalf = (wave >> 1) * 64;
  const int ml = lane & 15;      // m (or n) within 16-tile
  const int q  = lane >> 4;      // k-quad: holds k = q*8 .. q*8+7

  floatx4 acc[4][4];
  #pragma unroll
  for (int a = 0; a < 4; ++a)
    #pragma unroll
    for (int b = 0; b < 4; ++b) acc[a][b] = (floatx4){0.f, 0.f, 0.f, 0.f};

  for (int stage = 0; stage < 4; ++stage) {
    const unsigned short* __restrict__ Asrc = (stage < 2) ? A1 : A2;
    const float* __restrict__ Wsrc = (stage < 2) ? WL : WR;
    const int k0g = (stage & 1) * 64;
    if (stage) __syncthreads();   // all reads of previous stage done

    // stage A: 128 rows x 64 bf16 (16B per thread-iter, 4 iters)
    #pragma unroll
    for (int i = 0; i < 4; ++i) {
      int seg = t + i * 256;            // 0..1023
      int r = seg >> 3, kc = (seg & 7) * 8;
      int gr = row0 + r;
      float4 v = make_float4(0.f, 0.f, 0.f, 0.f);
      if (gr < M) v = *(const float4*)(Asrc + (size_t)gr * HID + k0g + kc);
      *(float4*)&sA[r * LDK + kc] = v;
    }
    // stage W: 128 rows x 64 fp32 -> bf16
    #pragma unroll
    for (int i = 0; i < 8; ++i) {
      int e = t + i * 256;              // 0..2047 quads
      int o = e >> 4, kc = (e & 15) * 4;
      float4 v = *(const float4*)(Wsrc + (size_t)o * HID + k0g + kc);
      uint32_t lo = (uint32_t)f2bf(v.x) | ((uint32_t)f2bf(v.y) << 16);
      uint32_t hi = (uint32_t)f2bf(v.z) | ((uint32_t)f2bf(v.w) << 16);
      *(uint2*)&sW[o * LDK + kc] = make_uint2(lo, hi);
    }
    __syncthreads();

    #pragma unroll
    for (int ks = 0; ks < 2; ++ks) {
      int kb = ks * 32 + q * 8;
      short8 af[4], bf[4];
      #pragma unroll
      for (int mt = 0; mt < 4; ++mt)
        af[mt] = *(const short8*)&sA[(mhalf + mt * 16 + ml) * LDK + kb];
      #pragma unroll
      for (int nt = 0; nt < 4; ++nt)
        bf[nt] = *(const short8*)&sW[(nhalf + nt * 16 + ml) * LDK + kb];
      #pragma unroll
      for (int mt = 0; mt < 4; ++mt)
        #pragma unroll
        for (int nt = 0; nt < 4; ++nt)
          acc[mt][nt] = __builtin_amdgcn_mfma_f32_16x16x32_bf16(af[mt], bf[nt], acc[mt][nt], 0, 0, 0);
    }
  }

  // epilogue: C/D layout col=lane&15, row=q*4+reg
  #pragma unroll
  for (int nt = 0; nt < 4; ++nt) {
    int gcol = nhalf + nt * 16 + ml;
    float bv = bias[gcol];
    #pragma unroll
    for (int mt = 0; mt < 4; ++mt) {
      #pragma unroll
      for (int r = 0; r < 4; ++r) {
        int grow = row0 + mhalf + mt * 16 + q * 4 + r;
        if (grow < M) {
          float v = acc[mt][nt][r] + bv;
          if (relu) v = fmaxf(v, 0.f);
          outb[(size_t)grow * HID + gcol] = f2bf(v);
        }
      }
    }
  }
}

// ---------------- fused mean-pool (bf16 in) + classifier (fp32) ----------------

__device__ __forceinline__ int lower_bound_dev(const int* a, int n, int key) {
  int lo = 0, hi = n;
  while (lo < hi) {
    int mid = (lo + hi) >> 1;
    if (a[mid] < key) lo = mid + 1; else hi = mid;
  }
  return lo;
}

__global__ __launch_bounds__(256) void k_pool_classify(const unsigned short* __restrict__ h,
                                                       const int* __restrict__ batch,
                                                       const float* __restrict__ cw,
                                                       const float* __restrict__ cb,
                                                       float* __restrict__ out, int N) {
  __shared__ int s_bounds[2];
  __shared__ float s_part[2][128];
  __shared__ float s_pool[128];
  int g = blockIdx.x;
  int t = threadIdx.x;
  if (t == 0) {
    s_bounds[0] = lower_bound_dev(batch, N, g);
    s_bounds[1] = lower_bound_dev(batch, N, g + 1);
  }
  __syncthreads();
  int lo = s_bounds[0], hi = s_bounds[1];
  int f = t & 127, half = t >> 7;
  float acc = 0.f;
  for (int n = lo + half; n < hi; n += 2)
    acc += __uint_as_float(((uint32_t)h[(size_t)n * HID + f]) << 16);
  s_part[half][f] = acc;
  __syncthreads();
  if (t < 128) {
    int cnt = hi - lo;
    float inv = 1.0f / (float)(cnt > 1 ? cnt : 1);
    s_pool[t] = (s_part[0][t] + s_part[1][t]) * inv;
  }
  __syncthreads();
  int o = t & 127, kh = t >> 7;
  float a2 = 0.f;
  #pragma unroll 4
  for (int k = kh * 64; k < kh * 64 + 64; ++k) a2 += s_pool[k] * cw[(size_t)o * HID + k];
  __syncthreads();
  s_part[kh][o] = a2;
  __syncthreads();
  if (t < 128) out[(size_t)g * HID + t] = s_part[0][t] + s_part[1][t] + cb[t];
}

// ---------------- launch ----------------

extern "C" void kernel_launch(void* const* d_in, const int* in_sizes, int n_in,
                              void* d_out, int out_size, void* d_ws, size_t ws_size,
                              hipStream_t stream) {
  const float* x     = (const float*)d_in[0];
  const int*   ei    = (const int*)d_in[1];
  const int*   batch = (const int*)d_in[2];
  const float* wl1   = (const float*)d_in[3];
  const float* b1    = (const float*)d_in[4];
  const float* wr1   = (const float*)d_in[5];
  const float* wl2   = (const float*)d_in[6];
  const float* b2    = (const float*)d_in[7];
  const float* wr2   = (const float*)d_in[8];
  const float* cw    = (const float*)d_in[9];
  const float* cb    = (const float*)d_in[10];
  float* out = (float*)d_out;

  const int N = in_sizes[0] / HID;   // 50000
  const int E = in_sizes[1] / 2;     // 800000
  const int G = out_size / HID;      // 128
  const int* src = ei;
  const int* dst = ei + E;

  char* w = (char*)d_ws;
  int* cursor = (int*)(w);                      // N ints
  int* rowptr = (int*)(w + 0x40000);            // N+1 ints (256KB offset)
  int* blks   = (int*)(w + 0x80000);            // <=256 ints
  int* csr    = (int*)(w + 0x80400);            // E ints (3.2MB)
  unsigned short* xb    = (unsigned short*)(w + 3725312);              // N*128 bf16 (12.8MB); h2 reuses this
  unsigned short* meanb = (unsigned short*)(w + 3725312 + 12800000);   // N*128 bf16
  unsigned short* h1b   = (unsigned short*)(w + 3725312 + 25600000);   // N*128 bf16
  unsigned short* h2b   = xb;  // xb dead after GEMM1 + aggregate1

  const int nblkN = (N + 255) / 256;
  const int nblkE = (E + 255) / 256;
  const int aggBlocks  = (N + 3) / 4;
  const int gemmBlocks = (N + 127) / 128;
  const int castBlocks = (N * HID / 4 + 255) / 256;

  hipLaunchKernelGGL(k_zero_int,    dim3(nblkN), dim3(256), 0, stream, cursor, N);
  hipLaunchKernelGGL(k_count,       dim3(nblkE), dim3(256), 0, stream, dst, cursor, E);
  hipLaunchKernelGGL(k_scan_blocks, dim3(nblkN), dim3(256), 0, stream, cursor, rowptr + 1, blks, N);
  hipLaunchKernelGGL(k_scan_top,    dim3(1),     dim3(256), 0, stream, blks, nblkN);
  hipLaunchKernelGGL(k_scan_add,    dim3(nblkN), dim3(256), 0, stream, blks, rowptr, cursor, N);
  hipLaunchKernelGGL(k_fill,        dim3(nblkE), dim3(256), 0, stream, src, dst, cursor, csr, E);

  hipLaunchKernelGGL(k_cast_bf16,   dim3(castBlocks), dim3(256), 0, stream, x, xb, N * HID / 4);

  // layer 1
  hipLaunchKernelGGL(k_aggregate, dim3(aggBlocks),  dim3(256), 0, stream, xb, rowptr, csr, meanb, N);
  hipLaunchKernelGGL(k_gemm_mfma, dim3(gemmBlocks), dim3(256), 0, stream, meanb, xb, wl1, wr1, b1, h1b, N, 1);
  // layer 2
  hipLaunchKernelGGL(k_aggregate, dim3(aggBlocks),  dim3(256), 0, stream, h1b, rowptr, csr, meanb, N);
  hipLaunchKernelGGL(k_gemm_mfma, dim3(gemmBlocks), dim3(256), 0, stream, meanb, h1b, wl2, wr2, b2, h2b, N, 1);
  // pool + classifier
  hipLaunchKernelGGL(k_pool_classify, dim3(G), dim3(256), 0, stream, h2b, batch, cw, cb, out, N);
}

// Round 3
// 299.576 us; speedup vs baseline: 1.7690x; 1.3109x over previous
//
#include <hip/hip_runtime.h>
#include <cstdint>
#include <cstddef>

#define HID 128
#define LDK 72   // LDS row stride in bf16 elems (64 + 8 pad)

typedef __attribute__((ext_vector_type(8))) short short8;
typedef __attribute__((ext_vector_type(4))) float floatx4;

__device__ __forceinline__ unsigned short f2bf(float f) {
  union { float f; uint32_t u; } c; c.f = f;
  uint32_t u = c.u;
  uint32_t r = (u + 0x7FFFu + ((u >> 16) & 1u)) >> 16;   // RNE
  return (unsigned short)r;
}
__device__ __forceinline__ float bflo(uint32_t v) { return __uint_as_float(v << 16); }
__device__ __forceinline__ float bfhi(uint32_t v) { return __uint_as_float(v & 0xFFFF0000u); }
__device__ __forceinline__ float bf2f(unsigned short s) { return __uint_as_float(((uint32_t)s) << 16); }

// ---------------- CSR build ----------------

__global__ __launch_bounds__(256) void k_zero_int(int* __restrict__ p, int n) {
  int i = blockIdx.x * 256 + threadIdx.x;
  if (i < n) p[i] = 0;
}

__global__ __launch_bounds__(256) void k_count(const int* __restrict__ dst,
                                               int* __restrict__ cnt, int E) {
  int i = blockIdx.x * 256 + threadIdx.x;
  if (i < E) atomicAdd(&cnt[dst[i]], 1);
}

__global__ __launch_bounds__(256) void k_scan_blocks(const int* __restrict__ cnt,
                                                     int* __restrict__ rowptr1,
                                                     int* __restrict__ blksum, int n) {
  __shared__ int s[256];
  int tid = threadIdx.x;
  int i = blockIdx.x * 256 + tid;
  int v = (i < n) ? cnt[i] : 0;
  s[tid] = v;
  __syncthreads();
  #pragma unroll
  for (int off = 1; off < 256; off <<= 1) {
    int add = (tid >= off) ? s[tid - off] : 0;
    __syncthreads();
    s[tid] += add;
    __syncthreads();
  }
  if (i < n) rowptr1[i] = s[tid];
  if (tid == 255) blksum[blockIdx.x] = s[255];
}

__global__ __launch_bounds__(256) void k_scan_top(int* __restrict__ blksum, int nblk) {
  __shared__ int s[256];
  int tid = threadIdx.x;
  int v = (tid < nblk) ? blksum[tid] : 0;
  s[tid] = v;
  __syncthreads();
  #pragma unroll
  for (int off = 1; off < 256; off <<= 1) {
    int add = (tid >= off) ? s[tid - off] : 0;
    __syncthreads();
    s[tid] += add;
    __syncthreads();
  }
  if (tid < nblk) blksum[tid] = s[tid] - v;  // exclusive
}

__global__ __launch_bounds__(256) void k_scan_add(const int* __restrict__ blkoff,
                                                  int* __restrict__ rowptr,
                                                  int* __restrict__ cursor, int n) {
  int i = blockIdx.x * 256 + threadIdx.x;
  if (i < n) {
    int add = blkoff[i >> 8];
    int incl = rowptr[i + 1] + add;
    rowptr[i + 1] = incl;
    cursor[i] = incl - cursor[i];
    if (i == 0) rowptr[0] = 0;
  }
}

__global__ __launch_bounds__(256) void k_fill(const int* __restrict__ src,
                                              const int* __restrict__ dst,
                                              int* __restrict__ cursor,
                                              int* __restrict__ csr, int E) {
  int i = blockIdx.x * 256 + threadIdx.x;
  if (i < E) {
    int pos = atomicAdd(&cursor[dst[i]], 1);
    csr[pos] = src[i];
  }
}

// ---------------- fp32 -> bf16 cast ----------------

__global__ __launch_bounds__(256) void k_cast_bf16(const float* __restrict__ src,
                                                   unsigned short* __restrict__ dst, int n4) {
  int i = blockIdx.x * 256 + threadIdx.x;
  if (i < n4) {
    float4 v = ((const float4*)src)[i];
    uint32_t lo = (uint32_t)f2bf(v.x) | ((uint32_t)f2bf(v.y) << 16);
    uint32_t hi = (uint32_t)f2bf(v.z) | ((uint32_t)f2bf(v.w) << 16);
    ((uint2*)dst)[i] = make_uint2(lo, hi);
  }
}

// ---------------- mean aggregation: one wave per node, 4 rows in flight ----------------
// lane = grp*16 + fl; grp handles neighbor row j+grp, fl handles features fl*8..fl*8+7
// (uint4 = 8 bf16 per lane). Final shfl_xor(16,32) combines the 4 row-groups.

__global__ __launch_bounds__(256) void k_aggregate(const unsigned short* __restrict__ feat,
                                                   const int* __restrict__ rowptr,
                                                   const int* __restrict__ csr,
                                                   unsigned short* __restrict__ outmean, int N) {
  int wid = blockIdx.x * 4 + (threadIdx.x >> 6);
  int lane = threadIdx.x & 63;
  if (wid >= N) return;
  int start = rowptr[wid];
  int end   = rowptr[wid + 1];
  const int grp = lane >> 4;
  const int fl  = lane & 15;
  float a[8];
  #pragma unroll
  for (int i = 0; i < 8; ++i) a[i] = 0.f;

  for (int base = start; base < end; base += 64) {
    int m = end - base;
    if (m > 64) m = 64;
    int sidx = (base + lane < end) ? csr[base + lane] : 0;
    for (int j = 0; j < m; j += 4) {
      int jj = j + grp;
      int s = __shfl(sidx, jj, 64);
      if (jj < m) {
        uint4 v = *(const uint4*)(feat + (size_t)s * HID + fl * 8);
        a[0] += bflo(v.x); a[1] += bfhi(v.x);
        a[2] += bflo(v.y); a[3] += bfhi(v.y);
        a[4] += bflo(v.z); a[5] += bfhi(v.z);
        a[6] += bflo(v.w); a[7] += bfhi(v.w);
      }
    }
  }
  #pragma unroll
  for (int i = 0; i < 8; ++i) {
    a[i] += __shfl_xor(a[i], 16, 64);
    a[i] += __shfl_xor(a[i], 32, 64);
  }
  if (grp == 0) {
    int deg = end - start;
    float inv = 1.0f / (float)(deg > 1 ? deg : 1);
    uint4 o;
    o.x = (uint32_t)f2bf(a[0] * inv) | ((uint32_t)f2bf(a[1] * inv) << 16);
    o.y = (uint32_t)f2bf(a[2] * inv) | ((uint32_t)f2bf(a[3] * inv) << 16);
    o.z = (uint32_t)f2bf(a[4] * inv) | ((uint32_t)f2bf(a[5] * inv) << 16);
    o.w = (uint32_t)f2bf(a[6] * inv) | ((uint32_t)f2bf(a[7] * inv) << 16);
    *(uint4*)(outmean + (size_t)wid * HID + fl * 8) = o;
  }
}

// ---------------- MFMA GEMM: relu(A1@WL^T + A2@WR^T + b) ----------------
// 128x128 block tile, 4 waves. If `pooled` != null, instead of writing rows,
// segment-reduce the tile by (sorted) batch id and atomicAdd into pooled[G][128].

__global__ __launch_bounds__(256, 2) void k_gemm_mfma(const unsigned short* __restrict__ A1,
                                                      const unsigned short* __restrict__ A2,
                                                      const float* __restrict__ WL,
                                                      const float* __restrict__ WR,
                                                      const float* __restrict__ bias,
                                                      unsigned short* __restrict__ outb,
                                                      const int* __restrict__ batch,
                                                      float* __restrict__ pooled,
                                                      int M, int relu) {
  __shared__ __align__(16) unsigned short sAB[2 * 128 * LDK];  // sA | sW; reused as sH (128*128)
  __shared__ int sB[128];
  unsigned short* sA = sAB;
  unsigned short* sW = sAB + 128 * LDK;
  const int t = threadIdx.x;
  const int lane = t & 63;
  const int wave = t >> 6;
  const int row0 = blockIdx.x * 128;
  const int mhalf = (wave & 1) * 64;
  const int nhalf = (wave >> 1) * 64;
  const int ml = lane & 15;
  const int q  = lane >> 4;

  floatx4 acc[4][4];
  #pragma unroll
  for (int a = 0; a < 4; ++a)
    #pragma unroll
    for (int b = 0; b < 4; ++b) acc[a][b] = (floatx4){0.f, 0.f, 0.f, 0.f};

  for (int stage = 0; stage < 4; ++stage) {
    const unsigned short* __restrict__ Asrc = (stage < 2) ? A1 : A2;
    const float* __restrict__ Wsrc = (stage < 2) ? WL : WR;
    const int k0g = (stage & 1) * 64;
    if (stage) __syncthreads();

    #pragma unroll
    for (int i = 0; i < 4; ++i) {
      int seg = t + i * 256;
      int r = seg >> 3, kc = (seg & 7) * 8;
      int gr = row0 + r;
      float4 v = make_float4(0.f, 0.f, 0.f, 0.f);
      if (gr < M) v = *(const float4*)(Asrc + (size_t)gr * HID + k0g + kc);
      *(float4*)&sA[r * LDK + kc] = v;
    }
    #pragma unroll
    for (int i = 0; i < 8; ++i) {
      int e = t + i * 256;
      int o = e >> 4, kc = (e & 15) * 4;
      float4 v = *(const float4*)(Wsrc + (size_t)o * HID + k0g + kc);
      uint32_t lo = (uint32_t)f2bf(v.x) | ((uint32_t)f2bf(v.y) << 16);
      uint32_t hi = (uint32_t)f2bf(v.z) | ((uint32_t)f2bf(v.w) << 16);
      *(uint2*)&sW[o * LDK + kc] = make_uint2(lo, hi);
    }
    __syncthreads();

    #pragma unroll
    for (int ks = 0; ks < 2; ++ks) {
      int kb = ks * 32 + q * 8;
      short8 af[4], bfr[4];
      #pragma unroll
      for (int mt = 0; mt < 4; ++mt)
        af[mt] = *(const short8*)&sA[(mhalf + mt * 16 + ml) * LDK + kb];
      #pragma unroll
      for (int nt = 0; nt < 4; ++nt)
        bfr[nt] = *(const short8*)&sW[(nhalf + nt * 16 + ml) * LDK + kb];
      #pragma unroll
      for (int mt = 0; mt < 4; ++mt)
        #pragma unroll
        for (int nt = 0; nt < 4; ++nt)
          acc[mt][nt] = __builtin_amdgcn_mfma_f32_16x16x32_bf16(af[mt], bfr[nt], acc[mt][nt], 0, 0, 0);
    }
  }

  if (pooled == nullptr) {
    // C/D layout: col=lane&15, row=q*4+reg
    #pragma unroll
    for (int nt = 0; nt < 4; ++nt) {
      int gcol = nhalf + nt * 16 + ml;
      float bv = bias[gcol];
      #pragma unroll
      for (int mt = 0; mt < 4; ++mt) {
        #pragma unroll
        for (int r = 0; r < 4; ++r) {
          int grow = row0 + mhalf + mt * 16 + q * 4 + r;
          if (grow < M) {
            float v = acc[mt][nt][r] + bv;
            if (relu) v = fmaxf(v, 0.f);
            outb[(size_t)grow * HID + gcol] = f2bf(v);
          }
        }
      }
    }
  } else {
    // fused mean-pool: dump tile to LDS (overlaying sA/sW), segment-reduce by batch id
    __syncthreads();  // all MFMA LDS reads complete before overwrite
    unsigned short* sH = sAB;  // [128 rows][128 cols]
    #pragma unroll
    for (int nt = 0; nt < 4; ++nt) {
      int gcol = nhalf + nt * 16 + ml;
      float bv = bias[gcol];
      #pragma unroll
      for (int mt = 0; mt < 4; ++mt) {
        #pragma unroll
        for (int r = 0; r < 4; ++r) {
          int lr = mhalf + mt * 16 + q * 4 + r;
          float v = acc[mt][nt][r] + bv;
          if (relu) v = fmaxf(v, 0.f);
          sH[lr * 128 + gcol] = f2bf(v);
        }
      }
    }
    if (t < 128) sB[t] = (row0 + t < M) ? batch[row0 + t] : -1;
    __syncthreads();
    const int f = t & 127, half = t >> 7;
    float pacc = 0.f;
    int curg = -1;
    for (int n = half; n < 128; n += 2) {
      int g = sB[n];
      if (g != curg) {
        if (curg >= 0) atomicAdd(&pooled[(size_t)curg * HID + f], pacc);
        curg = g; pacc = 0.f;
      }
      if (g >= 0) pacc += bf2f(sH[n * 128 + f]);
    }
    if (curg >= 0) atomicAdd(&pooled[(size_t)curg * HID + f], pacc);
  }
}

// ---------------- classifier: out = pooled/cnt @ cw^T + cb ----------------

__device__ __forceinline__ int lower_bound_dev(const int* a, int n, int key) {
  int lo = 0, hi = n;
  while (lo < hi) {
    int mid = (lo + hi) >> 1;
    if (a[mid] < key) lo = mid + 1; else hi = mid;
  }
  return lo;
}

__global__ __launch_bounds__(256) void k_classify(const float* __restrict__ pooled,
                                                  const int* __restrict__ batch,
                                                  const float* __restrict__ cw,
                                                  const float* __restrict__ cb,
                                                  float* __restrict__ out, int N) {
  __shared__ int bnds[2];
  __shared__ float sp[128];
  __shared__ float part[2][128];
  int g = blockIdx.x;
  int t = threadIdx.x;
  if (t == 0) bnds[0] = lower_bound_dev(batch, N, g);
  if (t == 1) bnds[1] = lower_bound_dev(batch, N, g + 1);
  __syncthreads();
  int cnt = bnds[1] - bnds[0];
  float inv = 1.0f / (float)(cnt > 1 ? cnt : 1);
  if (t < 128) sp[t] = pooled[(size_t)g * HID + t] * inv;
  __syncthreads();
  int o = t & 127, kh = t >> 7;
  float a = 0.f;
  #pragma unroll 4
  for (int k = kh * 64; k < kh * 64 + 64; ++k) a += sp[k] * cw[(size_t)o * HID + k];
  part[kh][o] = a;
  __syncthreads();
  if (t < 128) out[(size_t)g * HID + t] = part[0][t] + part[1][t] + cb[t];
}

// ---------------- launch ----------------

extern "C" void kernel_launch(void* const* d_in, const int* in_sizes, int n_in,
                              void* d_out, int out_size, void* d_ws, size_t ws_size,
                              hipStream_t stream) {
  const float* x     = (const float*)d_in[0];
  const int*   ei    = (const int*)d_in[1];
  const int*   batch = (const int*)d_in[2];
  const float* wl1   = (const float*)d_in[3];
  const float* b1    = (const float*)d_in[4];
  const float* wr1   = (const float*)d_in[5];
  const float* wl2   = (const float*)d_in[6];
  const float* b2    = (const float*)d_in[7];
  const float* wr2   = (const float*)d_in[8];
  const float* cw    = (const float*)d_in[9];
  const float* cb    = (const float*)d_in[10];
  float* out = (float*)d_out;

  const int N = in_sizes[0] / HID;   // 50000
  const int E = in_sizes[1] / 2;     // 800000
  const int G = out_size / HID;      // 128
  const int* src = ei;
  const int* dst = ei + E;

  char* w = (char*)d_ws;
  int* cursor = (int*)(w);                      // N ints
  int* rowptr = (int*)(w + 0x40000);            // N+1 ints
  int* blks   = (int*)(w + 0x80000);            // <=256 ints
  int* csr    = (int*)(w + 0x80400);            // E ints
  unsigned short* xb    = (unsigned short*)(w + 3725312);              // N*128 bf16
  unsigned short* meanb = (unsigned short*)(w + 3725312 + 12800000);   // N*128 bf16
  unsigned short* h1b   = (unsigned short*)(w + 3725312 + 25600000);   // N*128 bf16
  float* pooled         = (float*)(w + 3725312 + 38400000);            // G*128 fp32

  const int nblkN = (N + 255) / 256;
  const int nblkE = (E + 255) / 256;
  const int aggBlocks  = (N + 3) / 4;
  const int gemmBlocks = (N + 127) / 128;
  const int castBlocks = (N * HID / 4 + 255) / 256;

  hipLaunchKernelGGL(k_zero_int,    dim3(nblkN), dim3(256), 0, stream, cursor, N);
  hipLaunchKernelGGL(k_count,       dim3(nblkE), dim3(256), 0, stream, dst, cursor, E);
  hipLaunchKernelGGL(k_scan_blocks, dim3(nblkN), dim3(256), 0, stream, cursor, rowptr + 1, blks, N);
  hipLaunchKernelGGL(k_scan_top,    dim3(1),     dim3(256), 0, stream, blks, nblkN);
  hipLaunchKernelGGL(k_scan_add,    dim3(nblkN), dim3(256), 0, stream, blks, rowptr, cursor, N);
  hipLaunchKernelGGL(k_fill,        dim3(nblkE), dim3(256), 0, stream, src, dst, cursor, csr, E);

  hipLaunchKernelGGL(k_cast_bf16,   dim3(castBlocks), dim3(256), 0, stream, x, xb, N * HID / 4);
  hipLaunchKernelGGL(k_zero_int,    dim3((G * HID + 255) / 256), dim3(256), 0, stream, (int*)pooled, G * HID);

  // layer 1
  hipLaunchKernelGGL(k_aggregate, dim3(aggBlocks),  dim3(256), 0, stream, xb, rowptr, csr, meanb, N);
  hipLaunchKernelGGL(k_gemm_mfma, dim3(gemmBlocks), dim3(256), 0, stream, meanb, xb, wl1, wr1, b1, h1b,
                     (const int*)nullptr, (float*)nullptr, N, 1);
  // layer 2 + fused pool
  hipLaunchKernelGGL(k_aggregate, dim3(aggBlocks),  dim3(256), 0, stream, h1b, rowptr, csr, meanb, N);
  hipLaunchKernelGGL(k_gemm_mfma, dim3(gemmBlocks), dim3(256), 0, stream, meanb, h1b, wl2, wr2, b2,
                     (unsigned short*)nullptr, batch, pooled, N, 1);
  // classifier
  hipLaunchKernelGGL(k_classify, dim3(G), dim3(256), 0, stream, pooled, batch, cw, cb, out, N);
}

// Round 4
// 284.072 us; speedup vs baseline: 1.8655x; 1.0546x over previous
//
#include <hip/hip_runtime.h>
#include <cstdint>
#include <cstddef>

#define HID 128
#define LDK 72   // LDS row stride in bf16 elems (64 + 8 pad)
#define EPB 4096 // edges per block in bucket pass

typedef __attribute__((ext_vector_type(8))) short short8;
typedef __attribute__((ext_vector_type(4))) float floatx4;

__device__ __forceinline__ unsigned short f2bf(float f) {
  union { float f; uint32_t u; } c; c.f = f;
  uint32_t u = c.u;
  uint32_t r = (u + 0x7FFFu + ((u >> 16) & 1u)) >> 16;   // RNE
  return (unsigned short)r;
}
__device__ __forceinline__ float bflo(uint32_t v) { return __uint_as_float(v << 16); }
__device__ __forceinline__ float bfhi(uint32_t v) { return __uint_as_float(v & 0xFFFF0000u); }
__device__ __forceinline__ float bf2f(unsigned short s) { return __uint_as_float(((uint32_t)s) << 16); }

// ---------------- CSR build ----------------

__global__ __launch_bounds__(256) void k_zero_int(int* __restrict__ p, int n) {
  int i = blockIdx.x * 256 + threadIdx.x;
  if (i < n) p[i] = 0;
}

__global__ __launch_bounds__(256) void k_count(const int* __restrict__ dst,
                                               int* __restrict__ cnt, int E) {
  int i = blockIdx.x * 256 + threadIdx.x;
  if (i < E) atomicAdd(&cnt[dst[i]], 1);
}

__global__ __launch_bounds__(256) void k_scan_blocks(const int* __restrict__ cnt,
                                                     int* __restrict__ rowptr1,
                                                     int* __restrict__ blksum, int n) {
  __shared__ int s[256];
  int tid = threadIdx.x;
  int i = blockIdx.x * 256 + tid;
  int v = (i < n) ? cnt[i] : 0;
  s[tid] = v;
  __syncthreads();
  #pragma unroll
  for (int off = 1; off < 256; off <<= 1) {
    int add = (tid >= off) ? s[tid - off] : 0;
    __syncthreads();
    s[tid] += add;
    __syncthreads();
  }
  if (i < n) rowptr1[i] = s[tid];
  if (tid == 255) blksum[blockIdx.x] = s[255];
}

__global__ __launch_bounds__(256) void k_scan_top(int* __restrict__ blksum, int nblk) {
  __shared__ int s[256];
  int tid = threadIdx.x;
  int v = (tid < nblk) ? blksum[tid] : 0;
  s[tid] = v;
  __syncthreads();
  #pragma unroll
  for (int off = 1; off < 256; off <<= 1) {
    int add = (tid >= off) ? s[tid - off] : 0;
    __syncthreads();
    s[tid] += add;
    __syncthreads();
  }
  if (tid < nblk) blksum[tid] = s[tid] - v;  // exclusive
}

__global__ __launch_bounds__(256) void k_scan_add(const int* __restrict__ blkoff,
                                                  int* __restrict__ rowptr,
                                                  int* __restrict__ cursor, int n) {
  int i = blockIdx.x * 256 + threadIdx.x;
  if (i < n) {
    int add = blkoff[i >> 8];
    int incl = rowptr[i + 1] + add;
    rowptr[i + 1] = incl;
    cursor[i] = incl - cursor[i];
    if (i == 0) rowptr[0] = 0;
  }
}

// bcur[b] = rowptr[b<<8]  (bucket write cursor into ebuf); NB <= 256, one block
__global__ __launch_bounds__(256) void k_init_bcur(const int* __restrict__ rowptr,
                                                   int* __restrict__ bcur, int NB) {
  int t = threadIdx.x;
  if (t < NB) bcur[t] = rowptr[t << 8];
}

// bucket pass: group edges by dst>>8 into ebuf, packed (src | dst_low<<16).
// Requires N < 65536 (src fits 16 bits) — true here (N=50000).
__global__ __launch_bounds__(256) void k_bucket(const int* __restrict__ src,
                                                const int* __restrict__ dst,
                                                int* __restrict__ bcur,
                                                uint32_t* __restrict__ ebuf,
                                                int E, int NB) {
  __shared__ int hist[256];
  __shared__ int lcur[256];
  const int t = threadIdx.x;
  const int base = blockIdx.x * EPB;
  if (t < NB) hist[t] = 0;
  __syncthreads();

  uint32_t val[EPB / 256];
  int bk[EPB / 256];
  #pragma unroll
  for (int i = 0; i < EPB / 256; ++i) {
    int e = base + i * 256 + t;
    bk[i] = -1;
    if (e < E) {
      int d = dst[e];
      int s = src[e];
      bk[i] = d >> 8;
      val[i] = (uint32_t)s | ((uint32_t)(d & 255) << 16);
      atomicAdd(&hist[bk[i]], 1);
    }
  }
  __syncthreads();
  if (t < NB) {
    int c = hist[t];
    lcur[t] = c ? atomicAdd(&bcur[t], c) : 0;
  }
  __syncthreads();
  #pragma unroll
  for (int i = 0; i < EPB / 256; ++i) {
    if (bk[i] >= 0) {
      int pos = atomicAdd(&lcur[bk[i]], 1);
      ebuf[pos] = val[i];
    }
  }
}

// fill pass: one block per bucket; csr writes confined to this bucket's 16KB window.
__global__ __launch_bounds__(256) void k_bucket_fill(const uint32_t* __restrict__ ebuf,
                                                     const int* __restrict__ rowptr,
                                                     int* __restrict__ cursor,
                                                     int* __restrict__ csr, int N) {
  const int b = blockIdx.x;
  const int t = threadIdx.x;
  int n0 = b << 8;
  int n1 = (b + 1) << 8; if (n1 > N) n1 = N;
  int lo = rowptr[n0], hi = rowptr[n1];
  for (int i = lo + t; i < hi; i += 256) {
    uint32_t e = ebuf[i];
    int s = (int)(e & 0xFFFFu);
    int d = n0 | (int)(e >> 16);
    int pos = atomicAdd(&cursor[d], 1);
    csr[pos] = s;
  }
}

// ---------------- fp32 -> bf16 cast ----------------

__global__ __launch_bounds__(256) void k_cast_bf16(const float* __restrict__ src,
                                                   unsigned short* __restrict__ dst, int n4) {
  int i = blockIdx.x * 256 + threadIdx.x;
  if (i < n4) {
    float4 v = ((const float4*)src)[i];
    uint32_t lo = (uint32_t)f2bf(v.x) | ((uint32_t)f2bf(v.y) << 16);
    uint32_t hi = (uint32_t)f2bf(v.z) | ((uint32_t)f2bf(v.w) << 16);
    ((uint2*)dst)[i] = make_uint2(lo, hi);
  }
}

// ---------------- mean aggregation: one wave per node, 4 rows in flight ----------------

__global__ __launch_bounds__(256) void k_aggregate(const unsigned short* __restrict__ feat,
                                                   const int* __restrict__ rowptr,
                                                   const int* __restrict__ csr,
                                                   unsigned short* __restrict__ outmean, int N) {
  int wid = blockIdx.x * 4 + (threadIdx.x >> 6);
  int lane = threadIdx.x & 63;
  if (wid >= N) return;
  int start = rowptr[wid];
  int end   = rowptr[wid + 1];
  const int grp = lane >> 4;
  const int fl  = lane & 15;
  float a[8];
  #pragma unroll
  for (int i = 0; i < 8; ++i) a[i] = 0.f;

  for (int base = start; base < end; base += 64) {
    int m = end - base;
    if (m > 64) m = 64;
    int sidx = (base + lane < end) ? csr[base + lane] : 0;
    for (int j = 0; j < m; j += 4) {
      int jj = j + grp;
      int s = __shfl(sidx, jj, 64);
      if (jj < m) {
        uint4 v = *(const uint4*)(feat + (size_t)s * HID + fl * 8);
        a[0] += bflo(v.x); a[1] += bfhi(v.x);
        a[2] += bflo(v.y); a[3] += bfhi(v.y);
        a[4] += bflo(v.z); a[5] += bfhi(v.z);
        a[6] += bflo(v.w); a[7] += bfhi(v.w);
      }
    }
  }
  #pragma unroll
  for (int i = 0; i < 8; ++i) {
    a[i] += __shfl_xor(a[i], 16, 64);
    a[i] += __shfl_xor(a[i], 32, 64);
  }
  if (grp == 0) {
    int deg = end - start;
    float inv = 1.0f / (float)(deg > 1 ? deg : 1);
    uint4 o;
    o.x = (uint32_t)f2bf(a[0] * inv) | ((uint32_t)f2bf(a[1] * inv) << 16);
    o.y = (uint32_t)f2bf(a[2] * inv) | ((uint32_t)f2bf(a[3] * inv) << 16);
    o.z = (uint32_t)f2bf(a[4] * inv) | ((uint32_t)f2bf(a[5] * inv) << 16);
    o.w = (uint32_t)f2bf(a[6] * inv) | ((uint32_t)f2bf(a[7] * inv) << 16);
    *(uint4*)(outmean + (size_t)wid * HID + fl * 8) = o;
  }
}

// ---------------- MFMA GEMM: relu(A1@WL^T + A2@WR^T + b) ----------------

__global__ __launch_bounds__(256, 2) void k_gemm_mfma(const unsigned short* __restrict__ A1,
                                                      const unsigned short* __restrict__ A2,
                                                      const float* __restrict__ WL,
                                                      const float* __restrict__ WR,
                                                      const float* __restrict__ bias,
                                                      unsigned short* __restrict__ outb,
                                                      const int* __restrict__ batch,
                                                      float* __restrict__ pooled,
                                                      int M, int relu) {
  __shared__ __align__(16) unsigned short sAB[2 * 128 * LDK];  // sA | sW; reused as sH
  __shared__ int sB[128];
  unsigned short* sA = sAB;
  unsigned short* sW = sAB + 128 * LDK;
  const int t = threadIdx.x;
  const int lane = t & 63;
  const int wave = t >> 6;
  const int row0 = blockIdx.x * 128;
  const int mhalf = (wave & 1) * 64;
  const int nhalf = (wave >> 1) * 64;
  const int ml = lane & 15;
  const int q  = lane >> 4;

  floatx4 acc[4][4];
  #pragma unroll
  for (int a = 0; a < 4; ++a)
    #pragma unroll
    for (int b = 0; b < 4; ++b) acc[a][b] = (floatx4){0.f, 0.f, 0.f, 0.f};

  for (int stage = 0; stage < 4; ++stage) {
    const unsigned short* __restrict__ Asrc = (stage < 2) ? A1 : A2;
    const float* __restrict__ Wsrc = (stage < 2) ? WL : WR;
    const int k0g = (stage & 1) * 64;
    if (stage) __syncthreads();

    #pragma unroll
    for (int i = 0; i < 4; ++i) {
      int seg = t + i * 256;
      int r = seg >> 3, kc = (seg & 7) * 8;
      int gr = row0 + r;
      float4 v = make_float4(0.f, 0.f, 0.f, 0.f);
      if (gr < M) v = *(const float4*)(Asrc + (size_t)gr * HID + k0g + kc);
      *(float4*)&sA[r * LDK + kc] = v;
    }
    #pragma unroll
    for (int i = 0; i < 8; ++i) {
      int e = t + i * 256;
      int o = e >> 4, kc = (e & 15) * 4;
      float4 v = *(const float4*)(Wsrc + (size_t)o * HID + k0g + kc);
      uint32_t lo = (uint32_t)f2bf(v.x) | ((uint32_t)f2bf(v.y) << 16);
      uint32_t hi = (uint32_t)f2bf(v.z) | ((uint32_t)f2bf(v.w) << 16);
      *(uint2*)&sW[o * LDK + kc] = make_uint2(lo, hi);
    }
    __syncthreads();

    #pragma unroll
    for (int ks = 0; ks < 2; ++ks) {
      int kb = ks * 32 + q * 8;
      short8 af[4], bfr[4];
      #pragma unroll
      for (int mt = 0; mt < 4; ++mt)
        af[mt] = *(const short8*)&sA[(mhalf + mt * 16 + ml) * LDK + kb];
      #pragma unroll
      for (int nt = 0; nt < 4; ++nt)
        bfr[nt] = *(const short8*)&sW[(nhalf + nt * 16 + ml) * LDK + kb];
      #pragma unroll
      for (int mt = 0; mt < 4; ++mt)
        #pragma unroll
        for (int nt = 0; nt < 4; ++nt)
          acc[mt][nt] = __builtin_amdgcn_mfma_f32_16x16x32_bf16(af[mt], bfr[nt], acc[mt][nt], 0, 0, 0);
    }
  }

  if (pooled == nullptr) {
    #pragma unroll
    for (int nt = 0; nt < 4; ++nt) {
      int gcol = nhalf + nt * 16 + ml;
      float bv = bias[gcol];
      #pragma unroll
      for (int mt = 0; mt < 4; ++mt) {
        #pragma unroll
        for (int r = 0; r < 4; ++r) {
          int grow = row0 + mhalf + mt * 16 + q * 4 + r;
          if (grow < M) {
            float v = acc[mt][nt][r] + bv;
            if (relu) v = fmaxf(v, 0.f);
            outb[(size_t)grow * HID + gcol] = f2bf(v);
          }
        }
      }
    }
  } else {
    __syncthreads();
    unsigned short* sH = sAB;
    #pragma unroll
    for (int nt = 0; nt < 4; ++nt) {
      int gcol = nhalf + nt * 16 + ml;
      float bv = bias[gcol];
      #pragma unroll
      for (int mt = 0; mt < 4; ++mt) {
        #pragma unroll
        for (int r = 0; r < 4; ++r) {
          int lr = mhalf + mt * 16 + q * 4 + r;
          float v = acc[mt][nt][r] + bv;
          if (relu) v = fmaxf(v, 0.f);
          sH[lr * 128 + gcol] = f2bf(v);
        }
      }
    }
    if (t < 128) sB[t] = (row0 + t < M) ? batch[row0 + t] : -1;
    __syncthreads();
    const int f = t & 127, half = t >> 7;
    float pacc = 0.f;
    int curg = -1;
    for (int n = half; n < 128; n += 2) {
      int g = sB[n];
      if (g != curg) {
        if (curg >= 0) atomicAdd(&pooled[(size_t)curg * HID + f], pacc);
        curg = g; pacc = 0.f;
      }
      if (g >= 0) pacc += bf2f(sH[n * 128 + f]);
    }
    if (curg >= 0) atomicAdd(&pooled[(size_t)curg * HID + f], pacc);
  }
}

// ---------------- classifier ----------------

__device__ __forceinline__ int lower_bound_dev(const int* a, int n, int key) {
  int lo = 0, hi = n;
  while (lo < hi) {
    int mid = (lo + hi) >> 1;
    if (a[mid] < key) lo = mid + 1; else hi = mid;
  }
  return lo;
}

__global__ __launch_bounds__(256) void k_classify(const float* __restrict__ pooled,
                                                  const int* __restrict__ batch,
                                                  const float* __restrict__ cw,
                                                  const float* __restrict__ cb,
                                                  float* __restrict__ out, int N) {
  __shared__ int bnds[2];
  __shared__ float sp[128];
  __shared__ float part[2][128];
  int g = blockIdx.x;
  int t = threadIdx.x;
  if (t == 0) bnds[0] = lower_bound_dev(batch, N, g);
  if (t == 1) bnds[1] = lower_bound_dev(batch, N, g + 1);
  __syncthreads();
  int cnt = bnds[1] - bnds[0];
  float inv = 1.0f / (float)(cnt > 1 ? cnt : 1);
  if (t < 128) sp[t] = pooled[(size_t)g * HID + t] * inv;
  __syncthreads();
  int o = t & 127, kh = t >> 7;
  float a = 0.f;
  #pragma unroll 4
  for (int k = kh * 64; k < kh * 64 + 64; ++k) a += sp[k] * cw[(size_t)o * HID + k];
  part[kh][o] = a;
  __syncthreads();
  if (t < 128) out[(size_t)g * HID + t] = part[0][t] + part[1][t] + cb[t];
}

// ---------------- launch ----------------

extern "C" void kernel_launch(void* const* d_in, const int* in_sizes, int n_in,
                              void* d_out, int out_size, void* d_ws, size_t ws_size,
                              hipStream_t stream) {
  const float* x     = (const float*)d_in[0];
  const int*   ei    = (const int*)d_in[1];
  const int*   batch = (const int*)d_in[2];
  const float* wl1   = (const float*)d_in[3];
  const float* b1    = (const float*)d_in[4];
  const float* wr1   = (const float*)d_in[5];
  const float* wl2   = (const float*)d_in[6];
  const float* b2    = (const float*)d_in[7];
  const float* wr2   = (const float*)d_in[8];
  const float* cw    = (const float*)d_in[9];
  const float* cb    = (const float*)d_in[10];
  float* out = (float*)d_out;

  const int N = in_sizes[0] / HID;   // 50000 (must be < 65536 for edge packing)
  const int E = in_sizes[1] / 2;     // 800000
  const int G = out_size / HID;      // 128
  const int* src = ei;
  const int* dst = ei + E;

  char* w = (char*)d_ws;
  int* cursor = (int*)(w);                      // N ints
  int* rowptr = (int*)(w + 0x40000);            // N+1 ints
  int* blks   = (int*)(w + 0x80000);            // <=256 ints
  int* csr    = (int*)(w + 0x80400);            // E ints
  unsigned short* xb    = (unsigned short*)(w + 3725312);              // N*128 bf16
  unsigned short* meanb = (unsigned short*)(w + 3725312 + 12800000);   // N*128 bf16
  unsigned short* h1b   = (unsigned short*)(w + 3725312 + 25600000);   // N*128 bf16
  float* pooled         = (float*)(w + 3725312 + 38400000);            // G*128 fp32 (64KB)
  int* bcur             = (int*)(w + 3725312 + 38400000 + 65536);      // <=256 ints
  uint32_t* ebuf        = (uint32_t*)(w + 3725312 + 38400000 + 65536 + 1024);  // E uints

  const int NB = (N + 255) >> 8;     // 196 buckets
  const int nblkN = (N + 255) / 256;
  const int nblkE = (E + 255) / 256;
  const int aggBlocks  = (N + 3) / 4;
  const int gemmBlocks = (N + 127) / 128;
  const int castBlocks = (N * HID / 4 + 255) / 256;
  const int bktBlocks  = (E + EPB - 1) / EPB;

  hipLaunchKernelGGL(k_zero_int,    dim3(nblkN), dim3(256), 0, stream, cursor, N);
  hipLaunchKernelGGL(k_count,       dim3(nblkE), dim3(256), 0, stream, dst, cursor, E);
  hipLaunchKernelGGL(k_scan_blocks, dim3(nblkN), dim3(256), 0, stream, cursor, rowptr + 1, blks, N);
  hipLaunchKernelGGL(k_scan_top,    dim3(1),     dim3(256), 0, stream, blks, nblkN);
  hipLaunchKernelGGL(k_scan_add,    dim3(nblkN), dim3(256), 0, stream, blks, rowptr, cursor, N);
  hipLaunchKernelGGL(k_init_bcur,   dim3(1),     dim3(256), 0, stream, rowptr, bcur, NB);
  hipLaunchKernelGGL(k_bucket,      dim3(bktBlocks), dim3(256), 0, stream, src, dst, bcur, ebuf, E, NB);
  hipLaunchKernelGGL(k_bucket_fill, dim3(NB),    dim3(256), 0, stream, ebuf, rowptr, cursor, csr, N);

  hipLaunchKernelGGL(k_cast_bf16,   dim3(castBlocks), dim3(256), 0, stream, x, xb, N * HID / 4);
  hipLaunchKernelGGL(k_zero_int,    dim3((G * HID + 255) / 256), dim3(256), 0, stream, (int*)pooled, G * HID);

  // layer 1
  hipLaunchKernelGGL(k_aggregate, dim3(aggBlocks),  dim3(256), 0, stream, xb, rowptr, csr, meanb, N);
  hipLaunchKernelGGL(k_gemm_mfma, dim3(gemmBlocks), dim3(256), 0, stream, meanb, xb, wl1, wr1, b1, h1b,
                     (const int*)nullptr, (float*)nullptr, N, 1);
  // layer 2 + fused pool
  hipLaunchKernelGGL(k_aggregate, dim3(aggBlocks),  dim3(256), 0, stream, h1b, rowptr, csr, meanb, N);
  hipLaunchKernelGGL(k_gemm_mfma, dim3(gemmBlocks), dim3(256), 0, stream, meanb, h1b, wl2, wr2, b2,
                     (unsigned short*)nullptr, batch, pooled, N, 1);
  // classifier
  hipLaunchKernelGGL(k_classify, dim3(G), dim3(256), 0, stream, pooled, batch, cw, cb, out, N);
}